// Round 11
// baseline (384.883 us; speedup 1.0000x reference)
//
#include <hip/hip_runtime.h>
#include <hip/hip_fp16.h>

typedef _Float16 f16;
typedef _Float16 f16x8 __attribute__((ext_vector_type(8)));
typedef _Float16 f16x4 __attribute__((ext_vector_type(4)));
typedef float    f32x4 __attribute__((ext_vector_type(4)));

#define MFMA16(a, b, c) __builtin_amdgcn_mfma_f32_16x16x32_f16((a), (b), (c), 0, 0, 0)

#define BARR() __builtin_amdgcn_s_barrier()
#define VMW6() asm volatile("s_waitcnt vmcnt(6)" ::: "memory")
#define VMW2() asm volatile("s_waitcnt vmcnt(2)" ::: "memory")
#define VMW0() asm volatile("s_waitcnt vmcnt(0)" ::: "memory")

// global->LDS async, 16B/lane. Offset arg MUST be 0 (R4: imm applies to both
// global AND LDS address) — all offsets via pointer arithmetic.
#define GLOAD16(P, L)                                                          \
  __builtin_amdgcn_global_load_lds(                                            \
      (const __attribute__((address_space(1))) unsigned int*)(P),              \
      (__attribute__((address_space(3))) unsigned int*)(L), 16, 0, 0)

// ---------------- f32 -> f16 cast (x) ----------------
__global__ __launch_bounds__(256) void cast_f32_to_f16(const float* __restrict__ src,
                                                       f16* __restrict__ dst, int n4) {
  int i = blockIdx.x * 256 + threadIdx.x;
  if (i >= n4) return;
  float4 v = reinterpret_cast<const float4*>(src)[i];
  f16x4 o = { (f16)v.x, (f16)v.y, (f16)v.z, (f16)v.w };
  reinterpret_cast<f16x4*>(dst)[i] = o;
}

// ---------------- fused weight casts: Wq|Wk|Wv -> wqkvh, Wo -> woh ----------------
__global__ __launch_bounds__(256) void cast_weights(const float* __restrict__ Wq,
                                                    const float* __restrict__ Wk,
                                                    const float* __restrict__ Wv,
                                                    const float* __restrict__ Wo,
                                                    f16* __restrict__ wqkvh,
                                                    f16* __restrict__ woh) {
  const int k = blockIdx.x >> 10;
  const int i = (blockIdx.x & 1023) * 256 + threadIdx.x;   // < 262144 f32x4
  const float* src = (k == 0) ? Wq : (k == 1) ? Wk : (k == 2) ? Wv : Wo;
  f16* dst = (k == 3) ? woh : (wqkvh + k * 1048576);
  float4 v = reinterpret_cast<const float4*>(src)[i];
  f16x4 o = { (f16)v.x, (f16)v.y, (f16)v.z, (f16)v.w };
  reinterpret_cast<f16x4*>(dst)[i] = o;
}

// ============ 256x256 8-phase GEMM: C[M,N] = A[M,K] * B[N,K]^T, K=1024 ============
// 512 threads = 8 waves (2M x 4N), per-wave 128x64. BK=64, 2-buf 128 KiB LDS,
// st_16x32 swizzle, raw barriers, bx-fast XCD swizzle.
// POST-CLUSTER READ-AHEAD: every ds_read is issued AFTER the previous phase's
// MFMA cluster into just-freed frag regs (>=1 phase before consumption), so the
// LDS drain overlaps MFMA windows instead of serializing with them.
// Gate: one VMW(2)+barrier per tile at q3, confirming tile T+1 fully landed
// before q4-post cross-buffer reads (stage->gate distance >= 2 phases).
template <typename OutT>
__global__ __launch_bounds__(512, 1) void gemm_bt_8ph(const f16* __restrict__ A,
                                                      const f16* __restrict__ B,
                                                      OutT* __restrict__ C,
                                                      int N, int nbx) {
  constexpr int K = 1024;
  __shared__ f16 lds[2][2][2][8192];   // [buf][A/B][half][16KB]

  const int tid = threadIdx.x;
  const int wid = tid >> 6, l = tid & 63;
  const int wr = wid >> 2, wc = wid & 3;

  // T1: bijective XCD swizzle (nwg % 8 == 0); bx fast within the XCD chunk
  const int nwg = gridDim.x;
  const int cpx = nwg >> 3;
  const int id = blockIdx.x;
  const int swz = (id & 7) * cpx + (id >> 3);
  const int bx = swz % nbx, by = swz / nbx;

  // staging source coords: physical LDS slot (j*512+tid)*16B -> logical (row,col)
  // via the inverse (== same, XOR involution) st_16x32 swizzle
  int r0s, c0s, r1s, c1s;
  {
    int rel = tid * 16;
    int sub = rel >> 10, q = rel & 1023;
    int inner = q ^ (((q >> 9) & 1) << 5);
    r0s = ((sub >> 1) << 4) + (inner >> 6);
    c0s = ((sub & 1) << 5) + ((inner & 63) >> 1);
    rel = (512 + tid) * 16;
    sub = rel >> 10; q = rel & 1023;
    inner = q ^ (((q >> 9) & 1) << 5);
    r1s = ((sub >> 1) << 4) + (inner >> 6);
    c1s = ((sub & 1) << 5) + ((inner & 63) >> 1);
  }
  // staging pointers sit at the iteration's base tile (2i); advance 128/iter
  const f16* gA0a = A + (size_t)(by * 256 + r0s) * K + c0s;
  const f16* gA0b = A + (size_t)(by * 256 + r1s) * K + c1s;
  const f16* gA1a = gA0a + 128 * K;
  const f16* gA1b = gA0b + 128 * K;
  const f16* gB0a = B + (size_t)(bx * 256 + r0s) * K + c0s;
  const f16* gB0b = B + (size_t)(bx * 256 + r1s) * K + c1s;
  const f16* gB1a = gB0a + 128 * K;
  const f16* gB1b = gB0b + 128 * K;

#define STAGE_P(G0, G1, EOFF, LB, MAT, H)                                      \
  { GLOAD16((G0) + (EOFF), &lds[LB][MAT][H][wid * 512]);                       \
    GLOAD16((G1) + (EOFF), &lds[LB][MAT][H][4096 + wid * 512]); }

  // hoisted lane-dependent swizzled read base (bytes within a [128][64] region)
  const int lane_rd = (((l & 15) << 6) + ((l >> 4) << 4)) ^ (((l >> 3) & 1) << 5);
  const char* rdA0 = (const char*)&lds[0][0][wr][0] + lane_rd;
  const char* rdA1 = (const char*)&lds[1][0][wr][0] + lane_rd;
  const char* rdB0 = (const char*)&lds[0][1][wc >> 1][0] + (wc & 1) * 8192 + lane_rd;
  const char* rdB1 = (const char*)&lds[1][1][wc >> 1][0] + (wc & 1) * 8192 + lane_rd;

  f16x8 af[4][2], bf0[2][2], bf1[2][2];
  f32x4 acc[8][4] = {};

#define READ_A_MH(RD, mh)                                                      \
  _Pragma("unroll") for (int mm = 0; mm < 4; ++mm)                             \
  _Pragma("unroll") for (int ks = 0; ks < 2; ++ks)                             \
    af[mm][ks] = *reinterpret_cast<const f16x8*>(                              \
        (RD) + (((((mh)*4 + mm) * 2) + ks) << 10));
#define READ_B_NH(DST, RD, nh)                                                 \
  _Pragma("unroll") for (int nn = 0; nn < 2; ++nn)                             \
  _Pragma("unroll") for (int ks = 0; ks < 2; ++ks)                             \
    DST[nn][ks] = *reinterpret_cast<const f16x8*>(                             \
        (RD) + (((((nh)*2 + nn) * 2) + ks) << 10));
#define CL2(BF, mh, nh)                                                        \
  __builtin_amdgcn_s_setprio(1);                                               \
  _Pragma("unroll") for (int mm = 0; mm < 4; ++mm)                             \
  _Pragma("unroll") for (int nn = 0; nn < 2; ++nn)                             \
  _Pragma("unroll") for (int ks = 0; ks < 2; ++ks)                             \
    acc[(mh)*4 + mm][(nh)*2 + nn] =                                            \
        MFMA16(af[mm][ks], BF[nn][ks], acc[(mh)*4 + mm][(nh)*2 + nn]);         \
  __builtin_amdgcn_s_setprio(0);

  // prologue: tile0 full (buf0) + tile1 {B.h0,B.h1,A.h0} (buf1); 14 loads.
  STAGE_P(gB0a, gB0b, 0, 0, 1, 0);
  STAGE_P(gB1a, gB1b, 0, 0, 1, 1);
  STAGE_P(gA0a, gA0b, 0, 0, 0, 0);
  STAGE_P(gA1a, gA1b, 0, 0, 0, 1);
  STAGE_P(gB0a, gB0b, 64, 1, 1, 0);
  STAGE_P(gB1a, gB1b, 64, 1, 1, 1);
  STAGE_P(gA0a, gA0b, 64, 1, 0, 0);
  VMW6();            // tile0's 8 loads landed; tile1's 6 in flight
  BARR();
  // prologue reads (in-phase, once): tile0 mh0 + bf0
  READ_A_MH(rdA0, 0);
  READ_B_NH(bf0, rdB0, 0);

  for (int i = 0; i < 8; ++i) {
    const bool more = (i < 7);
    // ================= tile 2i (buf0) =================
    // q1: stage A.h1(2i+1)->buf1; CL2(mh0,bf0); post-read bf1(2i)
    STAGE_P(gA1a, gA1b, 64, 1, 0, 1);
    BARR();
    CL2(bf0, 0, 0);
    READ_B_NH(bf1, rdB0, 1);
    BARR();
    // q2: CL2(mh0,bf1); post-read af <- mh1(2i)  [af free after CL2 issue]
    BARR();
    CL2(bf1, 0, 1);
    READ_A_MH(rdA0, 1);
    BARR();
    // q3: stage B.h0(2i+2)->buf0 [buf0.B reads done by BARR2(q2)];
    //     CL2(mh1,bf1); gate: drain through q1's stage => tile 2i+1 landed
    if (more) STAGE_P(gB0a, gB0b, 128, 0, 1, 0);
    BARR();
    CL2(bf1, 1, 1);
    if (more) { VMW2(); } else { VMW0(); }
    BARR();
    // q4: stage B.h1 + A.h0 (2i+2)->buf0 [buf0.A reads done by BARR2(q2)->BARR2(q3)];
    //     CL2(mh1,bf0); post-read af <- mh0(2i+1), bf0 <- nh0(2i+1) from buf1
    if (more) { STAGE_P(gB1a, gB1b, 128, 0, 1, 1); STAGE_P(gA0a, gA0b, 128, 0, 0, 0); }
    BARR();
    CL2(bf0, 1, 0);
    READ_A_MH(rdA1, 0);
    READ_B_NH(bf0, rdB1, 0);
    BARR();
    // ================= tile 2i+1 (buf1) =================
    // q5: stage A.h1(2i+2)->buf0; CL2(mh0,bf0); post-read bf1(2i+1)
    if (more) STAGE_P(gA1a, gA1b, 128, 0, 0, 1);
    BARR();
    CL2(bf0, 0, 0);
    READ_B_NH(bf1, rdB1, 1);
    BARR();
    // q6: CL2(mh0,bf1); post-read af <- mh1(2i+1)
    BARR();
    CL2(bf1, 0, 1);
    READ_A_MH(rdA1, 1);
    BARR();
    // q7: stage B.h0(2i+3)->buf1; CL2(mh1,bf1); gate: tile 2i+2 landed
    if (more) STAGE_P(gB0a, gB0b, 192, 1, 1, 0);
    BARR();
    CL2(bf1, 1, 1);
    if (more) VMW2();
    BARR();
    // q8: stage B.h1 + A.h0 (2i+3)->buf1; CL2(mh1,bf0);
    //     post-read af <- mh0(2i+2), bf0 <- nh0(2i+2) from buf0
    if (more) { STAGE_P(gB1a, gB1b, 192, 1, 1, 1); STAGE_P(gA0a, gA0b, 192, 1, 0, 0); }
    BARR();
    CL2(bf0, 1, 0);
    if (more) { READ_A_MH(rdA0, 0); READ_B_NH(bf0, rdB0, 0); }
    BARR();
    gA0a += 128; gA0b += 128; gA1a += 128; gA1b += 128;
    gB0a += 128; gB0b += 128; gB1a += 128; gB1b += 128;
  }

  const int rr = by * 256 + wr * 128 + ((l >> 4) << 2);
  const int cc = bx * 256 + wc * 64 + (l & 15);
#pragma unroll
  for (int m = 0; m < 8; ++m)
#pragma unroll
    for (int n = 0; n < 4; ++n)
#pragma unroll
      for (int j = 0; j < 4; ++j)
        C[(size_t)(rr + m * 16 + j) * N + cc + n * 16] = (OutT)acc[m][n][j];
#undef STAGE_P
#undef READ_A_MH
#undef READ_B_NH
#undef CL2
}

// ---------------- scores: partial K-reduction (16 segments of 256 y) ----------------
__global__ __launch_bounds__(256, 2) void scores_part(const f16* __restrict__ qkv,
                                                      f16* __restrict__ part) {
  const int seg = blockIdx.x;            // 0..15
  const int bh = blockIdx.y;             // 0..127
  const int b = bh >> 4, h = bh & 15;
  const f16* base = qkv + (size_t)b * 4096 * 3072 + h * 64;   // Q; K at +1024

  __shared__ f16 sQ[64 * 264];           // Qt[qd][y], pitch 264
  __shared__ f16 sK[64 * 264];           // Kt[kd][y]

  const int tid = threadIdx.x;
  const int w = tid >> 6, l = tid & 63;

  const int tsel = w >> 1;               // 0: Q, 1: K
  const int g = ((w & 1) << 6) + l;      // 0..127
  const int r0 = g >> 1;                 // y-local 0..63 (+64*rep)
  const int ch = g & 1;                  // col-half (32 f16 = 64B)
  const f16* src = base + tsel * 1024 + (size_t)(seg * 256 + r0) * 3072 + ch * 32;
  f16* dstL = (tsel ? sK : sQ) + (ch * 32) * 264 + r0;

#pragma unroll
  for (int rep = 0; rep < 4; ++rep) {
    const f16* s0 = src + (size_t)(rep * 64) * 3072;
    f16x8 v0 = *reinterpret_cast<const f16x8*>(s0);
    f16x8 v1 = *reinterpret_cast<const f16x8*>(s0 + 8);
    f16x8 v2 = *reinterpret_cast<const f16x8*>(s0 + 16);
    f16x8 v3 = *reinterpret_cast<const f16x8*>(s0 + 24);
    f16* d = dstL + rep * 64;
#pragma unroll
    for (int j = 0; j < 8; ++j) {
      d[j * 264] = v0[j];
      d[(8 + j) * 264] = v1[j];
      d[(16 + j) * 264] = v2[j];
      d[(24 + j) * 264] = v3[j];
    }
  }
  __syncthreads();

  f32x4 acc[4] = {};
#pragma unroll
  for (int ys = 0; ys < 8; ++ys) {
    f16x8 a = *reinterpret_cast<const f16x8*>(sK + (w * 16 + (l & 15)) * 264 + ys * 32 + ((l >> 4) << 3));
#pragma unroll
    for (int n = 0; n < 4; ++n) {
      f16x8 bq = *reinterpret_cast<const f16x8*>(sQ + (n * 16 + (l & 15)) * 264 + ys * 32 + ((l >> 4) << 3));
      acc[n] = MFMA16(a, bq, acc[n]);
    }
  }

  f16* dst = part + ((size_t)(bh * 16 + seg)) * 4096;
#pragma unroll
  for (int n = 0; n < 4; ++n)
#pragma unroll
    for (int j = 0; j < 4; ++j)
      dst[(w * 16 + ((l >> 4) << 2) + j) * 64 + n * 16 + (l & 15)] = (f16)(acc[n][j] * 0.125f);
}

// ---------------- scores: combine partials + softmax -> Z^T ----------------
__global__ __launch_bounds__(256) void scores_combine(const f16* __restrict__ part,
                                                      f16* __restrict__ zt) {
  const int bh = blockIdx.x;
  const int kd = threadIdx.x >> 2;
  const int qg = threadIdx.x & 3;
  const f16* p0 = part + (size_t)bh * 16 * 4096 + kd * 64 + qg * 16;
  float s[16];
#pragma unroll
  for (int j = 0; j < 16; ++j) s[j] = 0.f;
#pragma unroll 4
  for (int seg = 0; seg < 16; ++seg) {
    f16x8 a = *reinterpret_cast<const f16x8*>(p0 + seg * 4096);
    f16x8 c = *reinterpret_cast<const f16x8*>(p0 + seg * 4096 + 8);
#pragma unroll
    for (int j = 0; j < 8; ++j) { s[j] += (float)a[j]; s[8 + j] += (float)c[j]; }
  }
  float mx = s[0];
#pragma unroll
  for (int j = 1; j < 16; ++j) mx = fmaxf(mx, s[j]);
  mx = fmaxf(mx, __shfl_xor(mx, 1));
  mx = fmaxf(mx, __shfl_xor(mx, 2));
  float sum = 0.f;
#pragma unroll
  for (int j = 0; j < 16; ++j) { float e = __expf(s[j] - mx); s[j] = e; sum += e; }
  sum += __shfl_xor(sum, 1);
  sum += __shfl_xor(sum, 2);
  float inv = 1.f / sum;
  f16* dst = zt + (size_t)bh * 4096 + (qg * 16) * 64 + kd;   // zt[q*64 + kd]
#pragma unroll
  for (int j = 0; j < 16; ++j) dst[j * 64] = (f16)(s[j] * inv);
}

// ---------------- PV + head merge ----------------
__global__ __launch_bounds__(256, 2) void pv_merge(const f16* __restrict__ qkv,
                                                   const f16* __restrict__ zt,
                                                   f16* __restrict__ out2) {
  const int st = blockIdx.x;
  const int bh = blockIdx.y;
  const int b = bh >> 4, h = bh & 15;
  const f16* vg = qkv + (size_t)(b * 4096 + st * 128) * 3072 + 2048 + h * 64;

  __shared__ f16 sV[128 * 72];
  __shared__ f16 sZ[64 * 72];

  const int tid = threadIdx.x;
  const int w = tid >> 6, l = tid & 63;

#pragma unroll
  for (int p = 0; p < 4; ++p) {
    int idx = (p * 256 + tid) * 8;
    int row = idx >> 6, col = idx & 63;
    f16x8 v = *reinterpret_cast<const f16x8*>(vg + (size_t)row * 3072 + col);
    *reinterpret_cast<f16x8*>(sV + row * 72 + col) = v;
  }
#pragma unroll
  for (int p = 0; p < 2; ++p) {
    int idx = (p * 256 + tid) * 8;
    int row = idx >> 6, col = idx & 63;
    f16x8 v = *reinterpret_cast<const f16x8*>(zt + (size_t)bh * 4096 + idx);
    *reinterpret_cast<f16x8*>(sZ + row * 72 + col) = v;
  }
  __syncthreads();

  f32x4 acc[2][4] = {};
#pragma unroll
  for (int ks = 0; ks < 2; ++ks) {
    f16x8 av[2], bz[4];
#pragma unroll
    for (int m = 0; m < 2; ++m)
      av[m] = *reinterpret_cast<const f16x8*>(sV + (w * 32 + m * 16 + (l & 15)) * 72 + ks * 32 + ((l >> 4) << 3));
#pragma unroll
    for (int n = 0; n < 4; ++n)
      bz[n] = *reinterpret_cast<const f16x8*>(sZ + (n * 16 + (l & 15)) * 72 + ks * 32 + ((l >> 4) << 3));
#pragma unroll
    for (int m = 0; m < 2; ++m)
#pragma unroll
      for (int n = 0; n < 4; ++n)
        acc[m][n] = MFMA16(av[m], bz[n], acc[m][n]);
  }

#pragma unroll
  for (int m = 0; m < 2; ++m)
#pragma unroll
    for (int n = 0; n < 4; ++n)
#pragma unroll
      for (int j = 0; j < 4; ++j) {
        int s = st * 128 + w * 32 + m * 16 + ((l >> 4) << 2) + j;
        out2[(size_t)(b * 4096 + s) * 1024 + h * 64 + n * 16 + (l & 15)] = (f16)acc[m][n][j];
      }
}

// ---------------- launch ----------------
extern "C" void kernel_launch(void* const* d_in, const int* in_sizes, int n_in,
                              void* d_out, int out_size, void* d_ws, size_t ws_size,
                              hipStream_t stream) {
  const float* x  = (const float*)d_in[0];
  const float* Wq = (const float*)d_in[1];
  const float* Wk = (const float*)d_in[2];
  const float* Wv = (const float*)d_in[3];
  const float* Wo = (const float*)d_in[4];
  float* out = (float*)d_out;

  f16* xh    = (f16*)d_ws;               //  33,554,432  x (f16); dead after QKV GEMM
  f16* qkvh  = xh + 33554432;            // 100,663,296  [32768 x 3072] q|k|v
  f16* wqkvh = qkvh + 100663296;         //   3,145,728  [3072 x 1024]
  f16* woh   = wqkvh + 3145728;          //   1,048,576  [1024 x 1024]
  f16* zth   = woh + 1048576;            //     524,288  [128][64 zq][64 kd]
  f16* out2h = zth + 524288;             //  33,554,432  [32768 x 1024] merged
  f16* part  = (f16*)d_ws;               // 16.8 MB f16 partial scores — reuses dead xh

  cast_f32_to_f16<<<32768, 256, 0, stream>>>(x, xh, 33554432 / 4);
  cast_weights<<<4096, 256, 0, stream>>>(Wq, Wk, Wv, Wo, wqkvh, woh);

  // QKV projection: [32768,3072] = xh * Wqkv^T   (1536 blocks, %8==0, bx fast)
  gemm_bt_8ph<f16><<<128 * 12, 512, 0, stream>>>(xh, wqkvh, qkvh, 3072, 12);

  // scores: 16-way split K-reduction (2048 blocks), then combine + softmax
  scores_part<<<dim3(16, 128), 256, 0, stream>>>(qkvh, part);
  scores_combine<<<128, 256, 0, stream>>>(part, zth);

  pv_merge<<<dim3(32, 128), 256, 0, stream>>>(qkvh, zth, out2h);

  // output projection: d_out = out2 * Wo^T (f32 out)   (512 blocks, %8==0, bx fast)
  gemm_bt_8ph<float><<<128 * 4, 512, 0, stream>>>(out2h, woh, out, 1024, 4);
}